// Round 12
// baseline (204.490 us; speedup 1.0000x reference)
//
#include <hip/hip_runtime.h>
#include <hip/hip_bf16.h>

// B=1, N=128, C=128, H=8, D=16. SCALE=0.25. All I/O fp32.
// GEMMs: bf16 MFMA, split-bf16 hi/lo 3-term for fp32 quality.
// Attention planes are HI-ONLY bf16. Plane arrays: [plane][dhalf][p][8] ushort.
// gemm_qkv v2: branches merged per block (A frags shared, 48 MFMA/kc),
// bf16 LDS tile (16.9KB), two-pass epilogue.
// attn v6: k-permutation k(c)=(c&15)*8+(c>>4) -> vector E/G loads.
// va layout: row p' = j*128+i, col k' = (br*8+h)*16 + d; gemm_out un-permutes.

#define NPOS 16384
#define CDIM 128

typedef __attribute__((ext_vector_type(8))) short bf16x8;
typedef __attribute__((ext_vector_type(8))) unsigned short u16x8;
typedef __attribute__((ext_vector_type(4))) float f32x4;

#define MFMA16(a, b, c) __builtin_amdgcn_mfma_f32_16x16x32_bf16((a), (b), (c), 0, 0, 0)

static __device__ __forceinline__ unsigned short f2bf(float x) {
    union { float f; unsigned int u; } v; v.f = x;
    unsigned int u = v.u;
    unsigned int r = u + 0x7FFFu + ((u >> 16) & 1u);   // RNE
    return (unsigned short)(r >> 16);
}
static __device__ __forceinline__ float bf2f(unsigned short h) {
    union { float f; unsigned int u; } v; v.u = ((unsigned int)h) << 16; return v.f;
}

// ---------------- LayerNorm: wave-per-row, no LDS ----------------
__global__ __launch_bounds__(256) void ln_kernel(
    const float* __restrict__ e,
    const float* __restrict__ w,
    const float* __restrict__ b,
    unsigned short* __restrict__ e_hl)
{
    const int t = threadIdx.x;
    const int lane = t & 63;
    const int row = blockIdx.x * 4 + (t >> 6);
    float2 x = *(const float2*)(e + (size_t)row * CDIM + lane * 2);
    float s = x.x + x.y, s2 = x.x * x.x + x.y * x.y;
    #pragma unroll
    for (int off = 1; off < 64; off <<= 1) {
        s  += __shfl_xor(s,  off, 64);
        s2 += __shfl_xor(s2, off, 64);
    }
    float m = s * (1.f / 128.f);
    float v = s2 * (1.f / 128.f) - m * m;
    float sc = rsqrtf(v + 1e-5f);
    float2 wv = *(const float2*)(w + lane * 2);
    float2 bv = *(const float2*)(b + lane * 2);
    float y0 = (x.x - m) * sc * wv.x + bv.x;
    float y1 = (x.y - m) * sc * wv.y + bv.y;
    unsigned short h0 = f2bf(y0), h1 = f2bf(y1);
    ushort2 hi = {h0, h1};
    ushort2 lo = {f2bf(y0 - bf2f(h0)), f2bf(y1 - bf2f(h1))};
    *(ushort2*)(e_hl + (size_t)row * 256 + lane * 2)       = hi;
    *(ushort2*)(e_hl + (size_t)row * 256 + 128 + lane * 2) = lo;
}

// ---------------- Weight packs ----------------
__global__ __launch_bounds__(256) void pack_qkv_w(
    const float* __restrict__ wq, const float* __restrict__ we,
    unsigned short* __restrict__ Bt)
{
    int idx = blockIdx.x * 256 + threadIdx.x;    // n*128 + k
    int n = idx >> 7, k = idx & 127;
    float v = 0.f;
    if (n < 384) v = wq[(size_t)k * 384 + n];
    else if (n < 400) v = we[(size_t)k * 16 + (n - 384)];
    unsigned short hi = f2bf(v);
    Bt[idx] = hi;
    Bt[448 * 128 + idx] = f2bf(v - bf2f(hi));
}

// w_o packed in k' = (br*8+h)*16 + d ordering (orig k = d*16 + br*8 + h).
__global__ __launch_bounds__(256) void pack_o_w(
    const float* __restrict__ wo, unsigned short* __restrict__ Bt)
{
    int idx = blockIdx.x * 256 + threadIdx.x;    // n*256 + kp
    int n = idx >> 8, kp = idx & 255;
    int d = kp & 15, pl = kp >> 4;
    int k = d * 16 + pl;
    float v = wo[(size_t)k * 128 + n];
    unsigned short hi = f2bf(v);
    Bt[idx] = hi;
    Bt[128 * 256 + idx] = f2bf(v - bf2f(hi));
}

// ---------------- MFMA GEMM v2: qkv+eg, branches merged ----------
// grid(128, 7), 256 thr. Tile 128(M) x 64(N) x 2(br). K=128, 48 MFMA/kc.
// by 0,1: Q d-halves; 2,3: K; 4,5: V; 6: eg (f32).
__global__ __launch_bounds__(256) void gemm_qkv_kernel(
    const unsigned short* __restrict__ e_hl,
    const unsigned short* __restrict__ B1t, const unsigned short* __restrict__ B2t,
    const float* __restrict__ bq_i, const float* __restrict__ be_i,
    const float* __restrict__ bq_o, const float* __restrict__ be_o,
    unsigned short* __restrict__ QT, unsigned short* __restrict__ KT,
    unsigned short* __restrict__ VT,
    float* __restrict__ eg_i, float* __restrict__ eg_o)
{
    const int t = threadIdx.x;
    const int wave = t >> 6, lane = t & 63;
    const int m = lane & 15, q = lane >> 4;
    const int bx = blockIdx.x;
    const int W0 = bx * 128 + wave * 32;
    const int by = blockIdx.y;
    const int N0 = by * 64;

    __shared__ unsigned short Ts16[128][66];   // 16.9 KB; also viewed as f32[128][33]

    f32x4 acc[2][2][4];   // [br][ms][ns]
    #pragma unroll
    for (int br = 0; br < 2; ++br)
        #pragma unroll
        for (int a = 0; a < 2; ++a)
            #pragma unroll
            for (int c = 0; c < 4; ++c) acc[br][a][c] = (f32x4){0.f, 0.f, 0.f, 0.f};

    const unsigned short* arow0 = e_hl + (size_t)(W0 + m) * 256;
    const unsigned short* arow1 = e_hl + (size_t)(W0 + 16 + m) * 256;
    const unsigned short* bcol[2][4];
    #pragma unroll
    for (int ns = 0; ns < 4; ++ns) {
        bcol[0][ns] = B1t + (size_t)(N0 + ns * 16 + m) * 128;
        bcol[1][ns] = B2t + (size_t)(N0 + ns * 16 + m) * 128;
    }

    #pragma unroll
    for (int kc = 0; kc < 4; ++kc) {
        const int ko = kc * 32 + q * 8;
        bf16x8 a0h = *(const bf16x8*)(arow0 + ko);
        bf16x8 a0l = *(const bf16x8*)(arow0 + 128 + ko);
        bf16x8 a1h = *(const bf16x8*)(arow1 + ko);
        bf16x8 a1l = *(const bf16x8*)(arow1 + 128 + ko);
        bf16x8 bh[2][4], bl[2][4];
        #pragma unroll
        for (int br = 0; br < 2; ++br)
            #pragma unroll
            for (int ns = 0; ns < 4; ++ns) {
                bh[br][ns] = *(const bf16x8*)(bcol[br][ns] + ko);
                bl[br][ns] = *(const bf16x8*)(bcol[br][ns] + 448 * 128 + ko);
            }
        #pragma unroll
        for (int br = 0; br < 2; ++br)
            #pragma unroll
            for (int ns = 0; ns < 4; ++ns) {
                acc[br][0][ns] = MFMA16(a0h, bh[br][ns], acc[br][0][ns]);
                acc[br][1][ns] = MFMA16(a1h, bh[br][ns], acc[br][1][ns]);
            }
        #pragma unroll
        for (int br = 0; br < 2; ++br)
            #pragma unroll
            for (int ns = 0; ns < 4; ++ns) {
                acc[br][0][ns] = MFMA16(a0l, bh[br][ns], acc[br][0][ns]);
                acc[br][1][ns] = MFMA16(a1l, bh[br][ns], acc[br][1][ns]);
            }
        #pragma unroll
        for (int br = 0; br < 2; ++br)
            #pragma unroll
            for (int ns = 0; ns < 4; ++ns) {
                acc[br][0][ns] = MFMA16(a0h, bl[br][ns], acc[br][0][ns]);
                acc[br][1][ns] = MFMA16(a1h, bl[br][ns], acc[br][1][ns]);
            }
    }

    // two-pass epilogue (one per branch), reusing the LDS tile
    #pragma unroll
    for (int br = 0; br < 2; ++br) {
        const float* bias_qkv = br ? bq_o : bq_i;
        const float* bias_eg  = br ? be_o : be_i;
        float* eg = br ? eg_o : eg_i;

        if (br) __syncthreads();   // ensure previous pass's reads done

        if (by < 6) {
            // stage as bf16 hi directly
            #pragma unroll
            for (int ms = 0; ms < 2; ++ms)
                #pragma unroll
                for (int ns = 0; ns < 4; ++ns) {
                    const int lc = ns * 16 + m;
                    const int col = N0 + lc;
                    const float bias = bias_qkv[col];
                    const float scale = (col < 128) ? 0.25f : 1.f;
                    #pragma unroll
                    for (int r = 0; r < 4; ++r) {
                        const int lr = wave * 32 + ms * 16 + q * 4 + r;
                        Ts16[lr][lc] = f2bf((acc[br][ms][ns][r] + bias) * scale);
                    }
                }
            __syncthreads();
            const int qsel = by >> 1, dhalf = by & 1;
            unsigned short* dstH = (qsel == 0) ? QT : (qsel == 1 ? KT : VT);
            #pragma unroll
            for (int it = 0; it < 4; ++it) {
                int item = it * 256 + t;        // 0..1023: (hh, lr)
                int hh = item >> 7, lr = item & 127;
                u16x8 hi;
                #pragma unroll
                for (int dd = 0; dd < 8; ++dd)
                    hi[dd] = Ts16[lr][dd * 8 + hh];
                size_t addr = (((size_t)(br * 8 + hh) * 2 + dhalf) * NPOS
                               + (size_t)bx * 128 + lr) * 8;   // i-major, dense
                *(u16x8*)(dstH + addr) = hi;
            }
        } else {
            // eg tile: only ns==0 cols are valid (384..399), stage as f32
            float* Tf = (float*)&Ts16[0][0];   // [128][33]
            #pragma unroll
            for (int ms = 0; ms < 2; ++ms) {
                const int col = N0 + m;        // 384 + m
                const float bias = bias_eg[m];
                #pragma unroll
                for (int r = 0; r < 4; ++r) {
                    const int lr = wave * 32 + ms * 16 + q * 4 + r;
                    Tf[lr * 33 + m] = acc[br][ms][0][r] + bias;
                }
                (void)col;
            }
            __syncthreads();
            #pragma unroll
            for (int it = 0; it < 2; ++it) {
                const int g = it * 256 + t;           // 0..511
                const int r128 = g >> 2, q4 = g & 3;
                float4 val;
                val.x = Tf[r128 * 33 + q4 * 4 + 0];
                val.y = Tf[r128 * 33 + q4 * 4 + 1];
                val.z = Tf[r128 * 33 + q4 * 4 + 2];
                val.w = Tf[r128 * 33 + q4 * 4 + 3];
                *(float4*)(eg + (size_t)(bx * 128 + r128) * 16 + q4 * 4) = val;
            }
        }
    }
}

// ---------------- In-place sub-plane transpose (i-major -> j-major) ----------
// Sub-plane = [128][128] matrix of 16B elements. grid(36, 64): x = tile pair
// (a<=b) of 16x16-element tiles, y = sub-plane selector:
//   0..31 QT (all), 32..47 KT (br=1), 48..63 VT (br=1).
__global__ __launch_bounds__(256) void transpose_kernel(
    unsigned short* __restrict__ QT, unsigned short* __restrict__ KT,
    unsigned short* __restrict__ VT)
{
    const int s = blockIdx.y;
    unsigned short* base;
    int sub;
    if (s < 32)       { base = QT; sub = s; }
    else if (s < 48)  { base = KT; sub = 16 + (s - 32); }
    else              { base = VT; sub = 16 + (s - 48); }
    unsigned short* P = base + (size_t)sub * NPOS * 8;

    int x = blockIdx.x, a = 0;
    while (x >= 8 - a) { x -= 8 - a; ++a; }
    const int b = a + x;

    __shared__ unsigned short T1[16][136];   // pad 8 -> 2-way max
    __shared__ unsigned short T2[16][136];

    const int t = threadIdx.x;
    const int r = t >> 4, c = t & 15;

    u16x8 v1 = *(const u16x8*)(P + ((size_t)(a * 16 + r) * 128 + b * 16 + c) * 8);
    *(u16x8*)&T1[r][c * 8] = v1;
    if (a != b) {
        u16x8 v2 = *(const u16x8*)(P + ((size_t)(b * 16 + r) * 128 + a * 16 + c) * 8);
        *(u16x8*)&T2[r][c * 8] = v2;
    }
    __syncthreads();

    u16x8 w1 = *(const u16x8*)&T1[c][r * 8];
    *(u16x8*)(P + ((size_t)(b * 16 + r) * 128 + a * 16 + c) * 8) = w1;
    if (a != b) {
        u16x8 w2 = *(const u16x8*)&T2[c][r * 8];
        *(u16x8*)(P + ((size_t)(a * 16 + r) * 128 + b * 16 + c) * 8) = w2;
    }
}

// ---------------- MFMA GEMM: output projection (va in p'/k' order) ----------------
// grid(256, 2), 256 thr. Tile 64(M) x 64(N). K=256. Row-permuted C store.
__global__ __launch_bounds__(256) void gemm_out_kernel(
    const float* __restrict__ va,
    const unsigned short* __restrict__ B3t,
    const float* __restrict__ bias,
    float* __restrict__ out)
{
    const int t = threadIdx.x;
    const int wave = t >> 6, lane = t & 63;
    const int m = lane & 15, q = lane >> 4;
    const int W0 = blockIdx.x * 64 + wave * 16;
    const int N0 = blockIdx.y * 64;

    f32x4 acc[4];
    #pragma unroll
    for (int c = 0; c < 4; ++c) acc[c] = (f32x4){0.f, 0.f, 0.f, 0.f};

    const float* arow = va + (size_t)(W0 + m) * 256;
    const unsigned short* bcol[4];
    #pragma unroll
    for (int ns = 0; ns < 4; ++ns)
        bcol[ns] = B3t + (size_t)(N0 + ns * 16 + m) * 256;

    #pragma unroll 2
    for (int kc = 0; kc < 8; ++kc) {
        const int ko = kc * 32 + q * 8;
        const float4* ap = (const float4*)(arow + ko);
        float4 f0 = ap[0], f1 = ap[1];
        float xs[8] = {f0.x, f0.y, f0.z, f0.w, f1.x, f1.y, f1.z, f1.w};
        bf16x8 ah, al;
        #pragma unroll
        for (int jj = 0; jj < 8; ++jj) {
            unsigned short h = f2bf(xs[jj]);
            ah[jj] = (short)h;
            al[jj] = (short)f2bf(xs[jj] - bf2f(h));
        }
        bf16x8 bh[4], bl[4];
        #pragma unroll
        for (int ns = 0; ns < 4; ++ns) {
            bh[ns] = *(const bf16x8*)(bcol[ns] + ko);
            bl[ns] = *(const bf16x8*)(bcol[ns] + 128 * 256 + ko);
        }
        #pragma unroll
        for (int ns = 0; ns < 4; ++ns) acc[ns] = MFMA16(ah, bh[ns], acc[ns]);
        #pragma unroll
        for (int ns = 0; ns < 4; ++ns) acc[ns] = MFMA16(al, bh[ns], acc[ns]);
        #pragma unroll
        for (int ns = 0; ns < 4; ++ns) acc[ns] = MFMA16(ah, bl[ns], acc[ns]);
    }

    #pragma unroll
    for (int ns = 0; ns < 4; ++ns) {
        const int col = N0 + ns * 16 + m;
        #pragma unroll
        for (int r = 0; r < 4; ++r) {
            const int prow = W0 + q * 4 + r;                 // p' = j*128+i
            const int orow = ((prow & 127) << 7) | (prow >> 7);  // i*128+j
            out[(size_t)orow * 128 + col] = acc[ns][r] + bias[col];
        }
    }
}

// ---------------- Bias/gate tables ----------------
__global__ __launch_bounds__(256) void tables_kernel(
    const float* __restrict__ eg_in, const float* __restrict__ eg_out,
    const float* __restrict__ mask,
    float* __restrict__ Etab, float* __restrict__ Gtab)
{
    int flat = blockIdx.x * 256 + threadIdx.x;   // 0..32767
    int br = flat >> 14;
    int p  = flat & 16383;
    const float* eg = br ? eg_out : eg_in;
    const float4* row = (const float4*)(eg + (size_t)p * 16);
    float4 r0 = row[0], r1 = row[1], r2 = row[2], r3 = row[3];
    float m = mask[p];
    float E[8] = {r0.x, r0.y, r0.z, r0.w, r1.x, r1.y, r1.z, r1.w};
    float G[8] = {r2.x, r2.y, r2.z, r2.w, r3.x, r3.y, r3.z, r3.w};
    int i, k;
    if (br == 0) { i = p >> 7; k = p & 127; }
    else         { k = p >> 7; i = p & 127; }
    int dst = i * 128 + k;
    #pragma unroll
    for (int h = 0; h < 8; ++h) {
        size_t off = (size_t)(br * 8 + h) * NPOS + dst;
        Etab[off] = E[h] + m;
        Gtab[off] = 1.f / (1.f + __expf(-(G[h] + m)));
    }
}

// ---------------- MFMA fused triangle attention v6 (permuted k, vector E/G) --
// grid (j=128, h=8, br=2), 256 thr = 4 waves, wave owns 32-row strip.
// S-column c maps to K-row k(c) = (c&15)*8 + (c>>4); softmax is k-permutation
// invariant, and P/V use the same order, so the result is exact.
__global__ __launch_bounds__(256) void attn_kernel(
    const unsigned short* __restrict__ QT, const unsigned short* __restrict__ KT,
    const unsigned short* __restrict__ VT,
    const float* __restrict__ Etab, const float* __restrict__ Gtab,
    float* __restrict__ va)
{
    const int j = blockIdx.x, h = blockIdx.y, br = blockIdx.z;
    const int t = threadIdx.x;
    const int wave = t >> 6, lane = t & 63;
    const int m = lane & 15, q = lane >> 4;
    const int plane = br * 8 + h;
    const size_t SP = (size_t)NPOS * 8;          // ushorts per sub-plane
    const size_t jb = (size_t)j * 128 * 8;
    const float* __restrict__ Eb = Etab + (size_t)plane * NPOS;
    const float* __restrict__ Gb = Gtab + (size_t)plane * NPOS;

    __shared__ unsigned short Vth[16 * 136];
    __shared__ unsigned short Pl[128 * 136];

    const int strip = wave * 32;

    // ---- E preload into the MFMA accumulator (contiguous float4 pairs) ----
    f32x4 S[2][8];
    #pragma unroll
    for (int mt = 0; mt < 2; ++mt)
        #pragma unroll
        for (int r = 0; r < 4; ++r) {
            const int i = strip + mt * 16 + q * 4 + r;
            const float* ep = Eb + (size_t)i * 128 + m * 8;
            f32x4 ea = *(const f32x4*)ep;
            f32x4 eb = *(const f32x4*)(ep + 4);
            #pragma unroll
            for (int nt = 0; nt < 4; ++nt) S[mt][nt][r]     = ea[nt];
            #pragma unroll
            for (int nt = 0; nt < 4; ++nt) S[mt][nt + 4][r] = eb[nt];
        }

    // stage V transposed+permuted into LDS: Vth[d*136 + c] = V[k(c)][d]
    {
        int c = t >> 1, ch = t & 1;
        int krow = (c & 15) * 8 + (c >> 4);
        const unsigned short* src = VT + (size_t)(plane * 2 + ch) * SP + jb
                                  + (size_t)krow * 8;
        u16x8 v = *(const u16x8*)src;
        #pragma unroll
        for (int dd = 0; dd < 8; ++dd)
            Vth[(ch * 8 + dd) * 136 + c] = v[dd];
    }

    const bf16x8 zero8 = {};
    const int hf = q & 1;
    const size_t qko = (size_t)(plane * 2 + hf) * SP + jb;

    // Q A-frags (direct from global; q>=2 lanes = zero K-half)
    bf16x8 aQ[2];
    #pragma unroll
    for (int mt = 0; mt < 2; ++mt) {
        const size_t off = qko + (size_t)(strip + mt * 16 + m) * 8;
        aQ[mt] = (q < 2) ? *(const bf16x8*)(QT + off) : zero8;
    }

    // S tiles: B row for tile nt, lane m = K row k = m*8 + nt (permuted)
    #pragma unroll
    for (int nt = 0; nt < 8; ++nt) {
        const size_t koff = qko + (size_t)(m * 8 + nt) * 8;
        bf16x8 bK = (q < 2) ? *(const bf16x8*)(KT + koff) : zero8;
        #pragma unroll
        for (int mt = 0; mt < 2; ++mt)
            S[mt][nt] = MFMA16(aQ[mt], bK, S[mt][nt]);
    }

    // softmax (row cols spread over lanes m: xor 1,2,4,8) + gate + P -> LDS
    #pragma unroll
    for (int mt = 0; mt < 2; ++mt)
        #pragma unroll
        for (int r = 0; r < 4; ++r) {
            float v = -1e30f;
            #pragma unroll
            for (int nt = 0; nt < 8; ++nt) v = fmaxf(v, S[mt][nt][r]);
            v = fmaxf(v, __shfl_xor(v, 1)); v = fmaxf(v, __shfl_xor(v, 2));
            v = fmaxf(v, __shfl_xor(v, 4)); v = fmaxf(v, __shfl_xor(v, 8));
            float s = 0.f;
            #pragma unroll
            for (int nt = 0; nt < 8; ++nt) {
                float p = __expf(S[mt][nt][r] - v);
                S[mt][nt][r] = p;
                s += p;
            }
            s += __shfl_xor(s, 1); s += __shfl_xor(s, 2);
            s += __shfl_xor(s, 4); s += __shfl_xor(s, 8);
            const float inv = 1.f / s;
            const int i = strip + mt * 16 + q * 4 + r;
            const float* gp = Gb + (size_t)i * 128 + m * 8;
            f32x4 ga = *(const f32x4*)gp;
            f32x4 gb = *(const f32x4*)(gp + 4);
            #pragma unroll
            for (int nt = 0; nt < 4; ++nt) {
                Pl[i * 136 + nt * 16 + m]       = f2bf(S[mt][nt][r] * inv * ga[nt]);
                Pl[i * 136 + (nt + 4) * 16 + m] = f2bf(S[mt][nt + 4][r] * inv * gb[nt]);
            }
        }

    __syncthreads();   // Vt ready (and P via lgkm drain)

    // AV = P @ V (both in permuted-k order)
    f32x4 av[2] = {(f32x4){0.f, 0.f, 0.f, 0.f}, (f32x4){0.f, 0.f, 0.f, 0.f}};
    #pragma unroll
    for (int kc = 0; kc < 4; ++kc) {
        const int off = kc * 32 + q * 8;
        bf16x8 bV = *(const bf16x8*)&Vth[m * 136 + off];
        #pragma unroll
        for (int mt = 0; mt < 2; ++mt) {
            bf16x8 aP = *(const bf16x8*)&Pl[(strip + mt * 16 + m) * 136 + off];
            av[mt] = MFMA16(aP, bV, av[mt]);
        }
    }

    // store va' (row p' = j*128+i, col k' = plane*16 + d): 64B-line coalesced
    #pragma unroll
    for (int mt = 0; mt < 2; ++mt)
        #pragma unroll
        for (int r = 0; r < 4; ++r) {
            const int i = strip + mt * 16 + q * 4 + r;
            va[((size_t)(j * 128 + i)) * 256 + plane * 16 + m] = av[mt][r];
        }
}

extern "C" void kernel_launch(void* const* d_in, const int* in_sizes, int n_in,
                              void* d_out, int out_size, void* d_ws, size_t ws_size,
                              hipStream_t stream) {
    const float* e        = (const float*)d_in[0];
    const float* mask     = (const float*)d_in[1];
    const float* ln_w     = (const float*)d_in[2];
    const float* ln_b     = (const float*)d_in[3];
    const float* w_qkv_in = (const float*)d_in[4];
    const float* b_qkv_in = (const float*)d_in[5];
    const float* w_eg_in  = (const float*)d_in[6];
    const float* b_eg_in  = (const float*)d_in[7];
    const float* w_qkv_o  = (const float*)d_in[8];
    const float* b_qkv_o  = (const float*)d_in[9];
    const float* w_eg_o   = (const float*)d_in[10];
    const float* b_eg_o   = (const float*)d_in[11];
    const float* w_o      = (const float*)d_in[12];
    const float* b_o      = (const float*)d_in[13];
    float* out = (float*)d_out;

    char* base = (char*)d_ws;
    const size_t PLANE = (size_t)16 * NPOS * 16;                      // ushorts per array
    unsigned short* e_hl = (unsigned short*)base;                     // 8.39 MB
    unsigned short* QT = (unsigned short*)(base + (size_t)NPOS * 256 * 2);
    unsigned short* KT = QT + PLANE;
    unsigned short* VT = KT + PLANE;
    float* eg_i = (float*)(VT + PLANE);                               // 1 MB
    float* eg_o = eg_i + (size_t)NPOS * 16;                           // 1 MB
    float* va   = eg_o + (size_t)NPOS * 16;                           // 16 MB

    // aliases (lifetime-checked): Etab/Gtab/B3t overlay dead e_hl region
    float* Etab = (float*)base;                                       // 1 MB
    float* Gtab = Etab + (size_t)2 * 8 * NPOS;                        // 1 MB
    unsigned short* B3t = (unsigned short*)(base + 2 * 1024 * 1024 + 256 * 1024);
    unsigned short* B1t = (unsigned short*)va;                        // dead before attn
    unsigned short* B2t = B1t + (size_t)2 * 448 * 128;

    ln_kernel<<<NPOS / 4, 256, 0, stream>>>(e, ln_w, ln_b, e_hl);

    pack_qkv_w<<<224, 256, 0, stream>>>(w_qkv_in, w_eg_in, B1t);
    pack_qkv_w<<<224, 256, 0, stream>>>(w_qkv_o,  w_eg_o,  B2t);

    gemm_qkv_kernel<<<dim3(128, 7), 256, 0, stream>>>(
        e_hl, B1t, B2t, b_qkv_in, b_eg_in, b_qkv_o, b_eg_o,
        QT, KT, VT, eg_i, eg_o);

    transpose_kernel<<<dim3(36, 64), 256, 0, stream>>>(QT, KT, VT);

    pack_o_w<<<128, 256, 0, stream>>>(w_o, B3t);   // e_hl dead now

    tables_kernel<<<128, 256, 0, stream>>>(eg_i, eg_o, mask, Etab, Gtab);

    attn_kernel<<<dim3(128, 8, 2), 256, 0, stream>>>(
        QT, KT, VT, Etab, Gtab, va);

    gemm_out_kernel<<<dim3(256, 2), 256, 0, stream>>>(va, B3t, b_o, out);
}

// Round 13
// 186.460 us; speedup vs baseline: 1.0967x; 1.0967x over previous
//
#include <hip/hip_runtime.h>
#include <hip/hip_bf16.h>

// B=1, N=128, C=128, H=8, D=16. SCALE=0.25. All I/O fp32.
// GEMMs: bf16 MFMA, split-bf16 hi/lo 3-term for fp32 quality.
// Attention planes are HI-ONLY bf16. Plane arrays: [plane][dhalf][p][8] ushort.
// gemm_qkv v3: global_load_lds staging (width 16, zero VGPR cost) of A+B per
// K-chunk, single-buffered; un-merged branches for register headroom.
// attn v6: k-permutation k(c)=(c&15)*8+(c>>4) -> vector E/G loads.
// va layout: row p' = j*128+i, col k' = (br*8+h)*16 + d; gemm_out un-permutes.

#define NPOS 16384
#define CDIM 128

typedef __attribute__((ext_vector_type(8))) short bf16x8;
typedef __attribute__((ext_vector_type(8))) unsigned short u16x8;
typedef __attribute__((ext_vector_type(4))) float f32x4;

#define MFMA16(a, b, c) __builtin_amdgcn_mfma_f32_16x16x32_bf16((a), (b), (c), 0, 0, 0)

#define GLL16(gp, lp) __builtin_amdgcn_global_load_lds( \
    (const __attribute__((address_space(1))) void*)(gp), \
    (__attribute__((address_space(3))) void*)(lp), 16, 0, 0)

static __device__ __forceinline__ unsigned short f2bf(float x) {
    union { float f; unsigned int u; } v; v.f = x;
    unsigned int u = v.u;
    unsigned int r = u + 0x7FFFu + ((u >> 16) & 1u);   // RNE
    return (unsigned short)(r >> 16);
}
static __device__ __forceinline__ float bf2f(unsigned short h) {
    union { float f; unsigned int u; } v; v.u = ((unsigned int)h) << 16; return v.f;
}

// ---------------- LayerNorm: wave-per-row, no LDS ----------------
__global__ __launch_bounds__(256) void ln_kernel(
    const float* __restrict__ e,
    const float* __restrict__ w,
    const float* __restrict__ b,
    unsigned short* __restrict__ e_hl)
{
    const int t = threadIdx.x;
    const int lane = t & 63;
    const int row = blockIdx.x * 4 + (t >> 6);
    float2 x = *(const float2*)(e + (size_t)row * CDIM + lane * 2);
    float s = x.x + x.y, s2 = x.x * x.x + x.y * x.y;
    #pragma unroll
    for (int off = 1; off < 64; off <<= 1) {
        s  += __shfl_xor(s,  off, 64);
        s2 += __shfl_xor(s2, off, 64);
    }
    float m = s * (1.f / 128.f);
    float v = s2 * (1.f / 128.f) - m * m;
    float sc = rsqrtf(v + 1e-5f);
    float2 wv = *(const float2*)(w + lane * 2);
    float2 bv = *(const float2*)(b + lane * 2);
    float y0 = (x.x - m) * sc * wv.x + bv.x;
    float y1 = (x.y - m) * sc * wv.y + bv.y;
    unsigned short h0 = f2bf(y0), h1 = f2bf(y1);
    ushort2 hi = {h0, h1};
    ushort2 lo = {f2bf(y0 - bf2f(h0)), f2bf(y1 - bf2f(h1))};
    *(ushort2*)(e_hl + (size_t)row * 256 + lane * 2)       = hi;
    *(ushort2*)(e_hl + (size_t)row * 256 + 128 + lane * 2) = lo;
}

// ---------------- Weight packs ----------------
__global__ __launch_bounds__(256) void pack_qkv_w(
    const float* __restrict__ wq, const float* __restrict__ we,
    unsigned short* __restrict__ Bt)
{
    int idx = blockIdx.x * 256 + threadIdx.x;    // n*128 + k
    int n = idx >> 7, k = idx & 127;
    float v = 0.f;
    if (n < 384) v = wq[(size_t)k * 384 + n];
    else if (n < 400) v = we[(size_t)k * 16 + (n - 384)];
    unsigned short hi = f2bf(v);
    Bt[idx] = hi;
    Bt[448 * 128 + idx] = f2bf(v - bf2f(hi));
}

// w_o packed in k' = (br*8+h)*16 + d ordering (orig k = d*16 + br*8 + h).
__global__ __launch_bounds__(256) void pack_o_w(
    const float* __restrict__ wo, unsigned short* __restrict__ Bt)
{
    int idx = blockIdx.x * 256 + threadIdx.x;    // n*256 + kp
    int n = idx >> 8, kp = idx & 255;
    int d = kp & 15, pl = kp >> 4;
    int k = d * 16 + pl;
    float v = wo[(size_t)k * 128 + n];
    unsigned short hi = f2bf(v);
    Bt[idx] = hi;
    Bt[128 * 256 + idx] = f2bf(v - bf2f(hi));
}

// ---------------- MFMA GEMM v3: qkv+eg, global_load_lds staging ----------
// grid(128, 7, 2), 256 thr. Tile 128(M) x 64(N). K=128 in 4 chunks.
// LDS: A [hl][q][128 row][16B] 16KB, B [hl][q][64 col][16B] 8KB (aliased by
// the epilogue Ts tile). by 0,1: Q d-halves; 2,3: K; 4,5: V; 6: eg (f32).
__global__ __launch_bounds__(256) void gemm_qkv_kernel(
    const unsigned short* __restrict__ e_hl,
    const unsigned short* __restrict__ B1t, const unsigned short* __restrict__ B2t,
    const float* __restrict__ bq_i, const float* __restrict__ be_i,
    const float* __restrict__ bq_o, const float* __restrict__ be_o,
    unsigned short* __restrict__ QT, unsigned short* __restrict__ KT,
    unsigned short* __restrict__ VT,
    float* __restrict__ eg_i, float* __restrict__ eg_o)
{
    __shared__ __align__(16) unsigned char smem[24576];
    unsigned short* Alds = (unsigned short*)smem;            // [2][4][128][8] ushorts
    unsigned short* Blds = (unsigned short*)(smem + 16384);  // [2][4][64][8]

    const int t = threadIdx.x;
    const int wave = t >> 6, lane = t & 63;
    const int m = lane & 15, q = lane >> 4;
    const int bx = blockIdx.x;
    const int W0blk = bx * 128;
    const int by = blockIdx.y;
    const int N0 = by * 64;
    const int br = blockIdx.z;
    const unsigned short* Bt = br ? B2t : B1t;
    const float* bias_qkv = br ? bq_o : bq_i;
    const float* bias_eg  = br ? be_o : be_i;
    float* eg = br ? eg_o : eg_i;

    f32x4 acc[2][4];
    #pragma unroll
    for (int a = 0; a < 2; ++a)
        #pragma unroll
        for (int c = 0; c < 4; ++c) acc[a][c] = (f32x4){0.f, 0.f, 0.f, 0.f};

    for (int kc = 0; kc < 4; ++kc) {
        // ---- stage A+B chunk into LDS: 24 wave-instrs, 6 per wave ----
        #pragma unroll
        for (int ii = 0; ii < 6; ++ii) {
            const int id = wave + ii * 4;
            if (id < 16) {
                const int hl = id >> 3, s = id & 7;
                const int qq = s >> 1, rbase = (s & 1) * 64;
                const unsigned short* g = e_hl
                    + (size_t)(W0blk + rbase + lane) * 256 + hl * 128 + kc * 32 + qq * 8;
                unsigned short* l = Alds + hl * 4096 + qq * 1024 + rbase * 8;
                GLL16(g, l);
            } else {
                const int id2 = id - 16;
                const int hl = id2 >> 2, qq = id2 & 3;
                const unsigned short* g = Bt + (size_t)(N0 + lane) * 128
                    + hl * (448 * 128) + kc * 32 + qq * 8;
                unsigned short* l = Blds + hl * 2048 + qq * 512;
                GLL16(g, l);
            }
        }
        __syncthreads();   // drains vmcnt: staged data visible

        bf16x8 aH[2], aL[2], bH[4], bL[4];
        #pragma unroll
        for (int ms = 0; ms < 2; ++ms) {
            const int row = wave * 32 + ms * 16 + m;
            aH[ms] = *(const bf16x8*)(Alds + 0    + q * 1024 + row * 8);
            aL[ms] = *(const bf16x8*)(Alds + 4096 + q * 1024 + row * 8);
        }
        #pragma unroll
        for (int ns = 0; ns < 4; ++ns) {
            bH[ns] = *(const bf16x8*)(Blds + 0    + q * 512 + (ns * 16 + m) * 8);
            bL[ns] = *(const bf16x8*)(Blds + 2048 + q * 512 + (ns * 16 + m) * 8);
        }
        #pragma unroll
        for (int ns = 0; ns < 4; ++ns) {
            acc[0][ns] = MFMA16(aH[0], bH[ns], acc[0][ns]);
            acc[1][ns] = MFMA16(aH[1], bH[ns], acc[1][ns]);
        }
        #pragma unroll
        for (int ns = 0; ns < 4; ++ns) {
            acc[0][ns] = MFMA16(aL[0], bH[ns], acc[0][ns]);
            acc[1][ns] = MFMA16(aL[1], bH[ns], acc[1][ns]);
        }
        #pragma unroll
        for (int ns = 0; ns < 4; ++ns) {
            acc[0][ns] = MFMA16(aH[0], bL[ns], acc[0][ns]);
            acc[1][ns] = MFMA16(aH[1], bL[ns], acc[1][ns]);
        }
        __syncthreads();   // LDS reusable (next chunk / epilogue)
    }

    // ---- epilogue: reuse smem as Ts16[128][66] (bf16) or Tf[128][33] (f32) ----
    if (by < 6) {
        unsigned short (*Ts16)[66] = (unsigned short (*)[66])smem;
        #pragma unroll
        for (int ms = 0; ms < 2; ++ms)
            #pragma unroll
            for (int ns = 0; ns < 4; ++ns) {
                const int lc = ns * 16 + m;
                const int col = N0 + lc;
                const float bias = bias_qkv[col];
                const float scale = (col < 128) ? 0.25f : 1.f;
                #pragma unroll
                for (int r = 0; r < 4; ++r) {
                    const int lr = wave * 32 + ms * 16 + q * 4 + r;
                    Ts16[lr][lc] = f2bf((acc[ms][ns][r] + bias) * scale);
                }
            }
        __syncthreads();
        const int qsel = by >> 1, dhalf = by & 1;
        unsigned short* dstH = (qsel == 0) ? QT : (qsel == 1 ? KT : VT);
        #pragma unroll
        for (int it = 0; it < 4; ++it) {
            int item = it * 256 + t;        // 0..1023: (hh, lr)
            int hh = item >> 7, lr = item & 127;
            u16x8 hi;
            #pragma unroll
            for (int dd = 0; dd < 8; ++dd)
                hi[dd] = Ts16[lr][dd * 8 + hh];
            size_t addr = (((size_t)(br * 8 + hh) * 2 + dhalf) * NPOS
                           + (size_t)bx * 128 + lr) * 8;   // i-major, dense
            *(u16x8*)(dstH + addr) = hi;
        }
    } else {
        float* Tf = (float*)smem;   // [128][33]
        #pragma unroll
        for (int ms = 0; ms < 2; ++ms) {
            const float bias = bias_eg[m];
            #pragma unroll
            for (int r = 0; r < 4; ++r) {
                const int lr = wave * 32 + ms * 16 + q * 4 + r;
                Tf[lr * 33 + m] = acc[ms][0][r] + bias;
            }
        }
        __syncthreads();
        #pragma unroll
        for (int it = 0; it < 2; ++it) {
            const int g = it * 256 + t;           // 0..511
            const int r128 = g >> 2, q4 = g & 3;
            float4 val;
            val.x = Tf[r128 * 33 + q4 * 4 + 0];
            val.y = Tf[r128 * 33 + q4 * 4 + 1];
            val.z = Tf[r128 * 33 + q4 * 4 + 2];
            val.w = Tf[r128 * 33 + q4 * 4 + 3];
            *(float4*)(eg + (size_t)(bx * 128 + r128) * 16 + q4 * 4) = val;
        }
    }
}

// ---------------- In-place sub-plane transpose (i-major -> j-major) ----------
// Sub-plane = [128][128] matrix of 16B elements. grid(36, 64): x = tile pair
// (a<=b) of 16x16-element tiles, y = sub-plane selector:
//   0..31 QT (all), 32..47 KT (br=1), 48..63 VT (br=1).
__global__ __launch_bounds__(256) void transpose_kernel(
    unsigned short* __restrict__ QT, unsigned short* __restrict__ KT,
    unsigned short* __restrict__ VT)
{
    const int s = blockIdx.y;
    unsigned short* base;
    int sub;
    if (s < 32)       { base = QT; sub = s; }
    else if (s < 48)  { base = KT; sub = 16 + (s - 32); }
    else              { base = VT; sub = 16 + (s - 48); }
    unsigned short* P = base + (size_t)sub * NPOS * 8;

    int x = blockIdx.x, a = 0;
    while (x >= 8 - a) { x -= 8 - a; ++a; }
    const int b = a + x;

    __shared__ unsigned short T1[16][136];   // pad 8 -> 2-way max
    __shared__ unsigned short T2[16][136];

    const int t = threadIdx.x;
    const int r = t >> 4, c = t & 15;

    u16x8 v1 = *(const u16x8*)(P + ((size_t)(a * 16 + r) * 128 + b * 16 + c) * 8);
    *(u16x8*)&T1[r][c * 8] = v1;
    if (a != b) {
        u16x8 v2 = *(const u16x8*)(P + ((size_t)(b * 16 + r) * 128 + a * 16 + c) * 8);
        *(u16x8*)&T2[r][c * 8] = v2;
    }
    __syncthreads();

    u16x8 w1 = *(const u16x8*)&T1[c][r * 8];
    *(u16x8*)(P + ((size_t)(b * 16 + r) * 128 + a * 16 + c) * 8) = w1;
    if (a != b) {
        u16x8 w2 = *(const u16x8*)&T2[c][r * 8];
        *(u16x8*)(P + ((size_t)(a * 16 + r) * 128 + b * 16 + c) * 8) = w2;
    }
}

// ---------------- MFMA GEMM: output projection (va in p'/k' order) ----------------
// grid(256, 2), 256 thr. Tile 64(M) x 64(N). K=256. Row-permuted C store.
__global__ __launch_bounds__(256) void gemm_out_kernel(
    const float* __restrict__ va,
    const unsigned short* __restrict__ B3t,
    const float* __restrict__ bias,
    float* __restrict__ out)
{
    const int t = threadIdx.x;
    const int wave = t >> 6, lane = t & 63;
    const int m = lane & 15, q = lane >> 4;
    const int W0 = blockIdx.x * 64 + wave * 16;
    const int N0 = blockIdx.y * 64;

    f32x4 acc[4];
    #pragma unroll
    for (int c = 0; c < 4; ++c) acc[c] = (f32x4){0.f, 0.f, 0.f, 0.f};

    const float* arow = va + (size_t)(W0 + m) * 256;
    const unsigned short* bcol[4];
    #pragma unroll
    for (int ns = 0; ns < 4; ++ns)
        bcol[ns] = B3t + (size_t)(N0 + ns * 16 + m) * 256;

    #pragma unroll 2
    for (int kc = 0; kc < 8; ++kc) {
        const int ko = kc * 32 + q * 8;
        const float4* ap = (const float4*)(arow + ko);
        float4 f0 = ap[0], f1 = ap[1];
        float xs[8] = {f0.x, f0.y, f0.z, f0.w, f1.x, f1.y, f1.z, f1.w};
        bf16x8 ah, al;
        #pragma unroll
        for (int jj = 0; jj < 8; ++jj) {
            unsigned short h = f2bf(xs[jj]);
            ah[jj] = (short)h;
            al[jj] = (short)f2bf(xs[jj] - bf2f(h));
        }
        bf16x8 bh[4], bl[4];
        #pragma unroll
        for (int ns = 0; ns < 4; ++ns) {
            bh[ns] = *(const bf16x8*)(bcol[ns] + ko);
            bl[ns] = *(const bf16x8*)(bcol[ns] + 128 * 256 + ko);
        }
        #pragma unroll
        for (int ns = 0; ns < 4; ++ns) acc[ns] = MFMA16(ah, bh[ns], acc[ns]);
        #pragma unroll
        for (int ns = 0; ns < 4; ++ns) acc[ns] = MFMA16(al, bh[ns], acc[ns]);
        #pragma unroll
        for (int ns = 0; ns < 4; ++ns) acc[ns] = MFMA16(ah, bl[ns], acc[ns]);
    }

    #pragma unroll
    for (int ns = 0; ns < 4; ++ns) {
        const int col = N0 + ns * 16 + m;
        #pragma unroll
        for (int r = 0; r < 4; ++r) {
            const int prow = W0 + q * 4 + r;                 // p' = j*128+i
            const int orow = ((prow & 127) << 7) | (prow >> 7);  // i*128+j
            out[(size_t)orow * 128 + col] = acc[ns][r] + bias[col];
        }
    }
}

// ---------------- Bias/gate tables ----------------
__global__ __launch_bounds__(256) void tables_kernel(
    const float* __restrict__ eg_in, const float* __restrict__ eg_out,
    const float* __restrict__ mask,
    float* __restrict__ Etab, float* __restrict__ Gtab)
{
    int flat = blockIdx.x * 256 + threadIdx.x;   // 0..32767
    int br = flat >> 14;
    int p  = flat & 16383;
    const float* eg = br ? eg_out : eg_in;
    const float4* row = (const float4*)(eg + (size_t)p * 16);
    float4 r0 = row[0], r1 = row[1], r2 = row[2], r3 = row[3];
    float m = mask[p];
    float E[8] = {r0.x, r0.y, r0.z, r0.w, r1.x, r1.y, r1.z, r1.w};
    float G[8] = {r2.x, r2.y, r2.z, r2.w, r3.x, r3.y, r3.z, r3.w};
    int i, k;
    if (br == 0) { i = p >> 7; k = p & 127; }
    else         { k = p >> 7; i = p & 127; }
    int dst = i * 128 + k;
    #pragma unroll
    for (int h = 0; h < 8; ++h) {
        size_t off = (size_t)(br * 8 + h) * NPOS + dst;
        Etab[off] = E[h] + m;
        Gtab[off] = 1.f / (1.f + __expf(-(G[h] + m)));
    }
}

// ---------------- MFMA fused triangle attention v6 (permuted k, vector E/G) --
// grid (j=128, h=8, br=2), 256 thr = 4 waves, wave owns 32-row strip.
// S-column c maps to K-row k(c) = (c&15)*8 + (c>>4); softmax is k-permutation
// invariant, and P/V use the same order, so the result is exact.
__global__ __launch_bounds__(256) void attn_kernel(
    const unsigned short* __restrict__ QT, const unsigned short* __restrict__ KT,
    const unsigned short* __restrict__ VT,
    const float* __restrict__ Etab, const float* __restrict__ Gtab,
    float* __restrict__ va)
{
    const int j = blockIdx.x, h = blockIdx.y, br = blockIdx.z;
    const int t = threadIdx.x;
    const int wave = t >> 6, lane = t & 63;
    const int m = lane & 15, q = lane >> 4;
    const int plane = br * 8 + h;
    const size_t SP = (size_t)NPOS * 8;          // ushorts per sub-plane
    const size_t jb = (size_t)j * 128 * 8;
    const float* __restrict__ Eb = Etab + (size_t)plane * NPOS;
    const float* __restrict__ Gb = Gtab + (size_t)plane * NPOS;

    __shared__ unsigned short Vth[16 * 136];
    __shared__ unsigned short Pl[128 * 136];

    const int strip = wave * 32;

    // ---- E preload into the MFMA accumulator (contiguous float4 pairs) ----
    f32x4 S[2][8];
    #pragma unroll
    for (int mt = 0; mt < 2; ++mt)
        #pragma unroll
        for (int r = 0; r < 4; ++r) {
            const int i = strip + mt * 16 + q * 4 + r;
            const float* ep = Eb + (size_t)i * 128 + m * 8;
            f32x4 ea = *(const f32x4*)ep;
            f32x4 eb = *(const f32x4*)(ep + 4);
            #pragma unroll
            for (int nt = 0; nt < 4; ++nt) S[mt][nt][r]     = ea[nt];
            #pragma unroll
            for (int nt = 0; nt < 4; ++nt) S[mt][nt + 4][r] = eb[nt];
        }

    // stage V transposed+permuted into LDS: Vth[d*136 + c] = V[k(c)][d]
    {
        int c = t >> 1, ch = t & 1;
        int krow = (c & 15) * 8 + (c >> 4);
        const unsigned short* src = VT + (size_t)(plane * 2 + ch) * SP + jb
                                  + (size_t)krow * 8;
        u16x8 v = *(const u16x8*)src;
        #pragma unroll
        for (int dd = 0; dd < 8; ++dd)
            Vth[(ch * 8 + dd) * 136 + c] = v[dd];
    }

    const bf16x8 zero8 = {};
    const int hf = q & 1;
    const size_t qko = (size_t)(plane * 2 + hf) * SP + jb;

    // Q A-frags (direct from global; q>=2 lanes = zero K-half)
    bf16x8 aQ[2];
    #pragma unroll
    for (int mt = 0; mt < 2; ++mt) {
        const size_t off = qko + (size_t)(strip + mt * 16 + m) * 8;
        aQ[mt] = (q < 2) ? *(const bf16x8*)(QT + off) : zero8;
    }

    // S tiles: B row for tile nt, lane m = K row k = m*8 + nt (permuted)
    #pragma unroll
    for (int nt = 0; nt < 8; ++nt) {
        const size_t koff = qko + (size_t)(m * 8 + nt) * 8;
        bf16x8 bK = (q < 2) ? *(const bf16x8*)(KT + koff) : zero8;
        #pragma unroll
        for (int mt = 0; mt < 2; ++mt)
            S[mt][nt] = MFMA16(aQ[mt], bK, S[mt][nt]);
    }

    // softmax (row cols spread over lanes m: xor 1,2,4,8) + gate + P -> LDS
    #pragma unroll
    for (int mt = 0; mt < 2; ++mt)
        #pragma unroll
        for (int r = 0; r < 4; ++r) {
            float v = -1e30f;
            #pragma unroll
            for (int nt = 0; nt < 8; ++nt) v = fmaxf(v, S[mt][nt][r]);
            v = fmaxf(v, __shfl_xor(v, 1)); v = fmaxf(v, __shfl_xor(v, 2));
            v = fmaxf(v, __shfl_xor(v, 4)); v = fmaxf(v, __shfl_xor(v, 8));
            float s = 0.f;
            #pragma unroll
            for (int nt = 0; nt < 8; ++nt) {
                float p = __expf(S[mt][nt][r] - v);
                S[mt][nt][r] = p;
                s += p;
            }
            s += __shfl_xor(s, 1); s += __shfl_xor(s, 2);
            s += __shfl_xor(s, 4); s += __shfl_xor(s, 8);
            const float inv = 1.f / s;
            const int i = strip + mt * 16 + q * 4 + r;
            const float* gp = Gb + (size_t)i * 128 + m * 8;
            f32x4 ga = *(const f32x4*)gp;
            f32x4 gb = *(const f32x4*)(gp + 4);
            #pragma unroll
            for (int nt = 0; nt < 4; ++nt) {
                Pl[i * 136 + nt * 16 + m]       = f2bf(S[mt][nt][r] * inv * ga[nt]);
                Pl[i * 136 + (nt + 4) * 16 + m] = f2bf(S[mt][nt + 4][r] * inv * gb[nt]);
            }
        }

    __syncthreads();   // Vt ready (and P via lgkm drain)

    // AV = P @ V (both in permuted-k order)
    f32x4 av[2] = {(f32x4){0.f, 0.f, 0.f, 0.f}, (f32x4){0.f, 0.f, 0.f, 0.f}};
    #pragma unroll
    for (int kc = 0; kc < 4; ++kc) {
        const int off = kc * 32 + q * 8;
        bf16x8 bV = *(const bf16x8*)&Vth[m * 136 + off];
        #pragma unroll
        for (int mt = 0; mt < 2; ++mt) {
            bf16x8 aP = *(const bf16x8*)&Pl[(strip + mt * 16 + m) * 136 + off];
            av[mt] = MFMA16(aP, bV, av[mt]);
        }
    }

    // store va' (row p' = j*128+i, col k' = plane*16 + d): 64B-line coalesced
    #pragma unroll
    for (int mt = 0; mt < 2; ++mt)
        #pragma unroll
        for (int r = 0; r < 4; ++r) {
            const int i = strip + mt * 16 + q * 4 + r;
            va[((size_t)(j * 128 + i)) * 256 + plane * 16 + m] = av[mt][r];
        }
}

extern "C" void kernel_launch(void* const* d_in, const int* in_sizes, int n_in,
                              void* d_out, int out_size, void* d_ws, size_t ws_size,
                              hipStream_t stream) {
    const float* e        = (const float*)d_in[0];
    const float* mask     = (const float*)d_in[1];
    const float* ln_w     = (const float*)d_in[2];
    const float* ln_b     = (const float*)d_in[3];
    const float* w_qkv_in = (const float*)d_in[4];
    const float* b_qkv_in = (const float*)d_in[5];
    const float* w_eg_in  = (const float*)d_in[6];
    const float* b_eg_in  = (const float*)d_in[7];
    const float* w_qkv_o  = (const float*)d_in[8];
    const float* b_qkv_o  = (const float*)d_in[9];
    const float* w_eg_o   = (const float*)d_in[10];
    const float* b_eg_o   = (const float*)d_in[11];
    const float* w_o      = (const float*)d_in[12];
    const float* b_o      = (const float*)d_in[13];
    float* out = (float*)d_out;

    char* base = (char*)d_ws;
    const size_t PLANE = (size_t)16 * NPOS * 16;                      // ushorts per array
    unsigned short* e_hl = (unsigned short*)base;                     // 8.39 MB
    unsigned short* QT = (unsigned short*)(base + (size_t)NPOS * 256 * 2);
    unsigned short* KT = QT + PLANE;
    unsigned short* VT = KT + PLANE;
    float* eg_i = (float*)(VT + PLANE);                               // 1 MB
    float* eg_o = eg_i + (size_t)NPOS * 16;                           // 1 MB
    float* va   = eg_o + (size_t)NPOS * 16;                           // 16 MB

    // aliases (lifetime-checked): Etab/Gtab/B3t overlay dead e_hl region
    float* Etab = (float*)base;                                       // 1 MB
    float* Gtab = Etab + (size_t)2 * 8 * NPOS;                        // 1 MB
    unsigned short* B3t = (unsigned short*)(base + 2 * 1024 * 1024 + 256 * 1024);
    unsigned short* B1t = (unsigned short*)va;                        // dead before attn
    unsigned short* B2t = B1t + (size_t)2 * 448 * 128;

    ln_kernel<<<NPOS / 4, 256, 0, stream>>>(e, ln_w, ln_b, e_hl);

    pack_qkv_w<<<224, 256, 0, stream>>>(w_qkv_in, w_eg_in, B1t);
    pack_qkv_w<<<224, 256, 0, stream>>>(w_qkv_o,  w_eg_o,  B2t);

    gemm_qkv_kernel<<<dim3(128, 7, 2), 256, 0, stream>>>(
        e_hl, B1t, B2t, b_qkv_in, b_eg_in, b_qkv_o, b_eg_o,
        QT, KT, VT, eg_i, eg_o);

    transpose_kernel<<<dim3(36, 64), 256, 0, stream>>>(QT, KT, VT);

    pack_o_w<<<128, 256, 0, stream>>>(w_o, B3t);   // e_hl dead now

    tables_kernel<<<128, 256, 0, stream>>>(eg_i, eg_o, mask, Etab, Gtab);

    attn_kernel<<<dim3(128, 8, 2), 256, 0, stream>>>(
        QT, KT, VT, Etab, Gtab, va);

    gemm_out_kernel<<<dim3(256, 2), 256, 0, stream>>>(va, B3t, b_o, out);
}